// Round 10
// baseline (347.136 us; speedup 1.0000x reference)
//
#include <hip/hip_runtime.h>

// Swin window attention, fused register-resident MFMA pipeline. 1 block
// (6 waves) per window; wave w owns head w. B=4096, N=64, C=180, H=6, D=30.
//
// Round-10 = round-9 (290 us) + exposed-latency code-motion + T5 setprio:
//   - mask it0 prefetched BEFORE the qk-pass (hides ~900cyc HBM under ~3k MFMA)
//   - softmax issues it+1 mask+bias loads BEFORE the QK^T MFMA cluster
//   - v-pass ks0 weights pre-issued before the softmax->v fence;
//     proj ks0 weights + bias pre-issued before the PV fence
//   - s_setprio(1) around every MFMA cluster (two blocks/CU at different
//     phases -> scheduler role diversity, T5)
//
// d_ws (prep_w fills every launch):
//   [0)       wqkvT  bf16 [576][192]  oc = h*96 + sec*32 + d  (0=q,1=k,2=v)
//   [221184)  wprojT bf16 [192][192]  n-major
//   [294912)  relb   f32  [6][64][64] pre-gathered rel-pos bias
//
// LDS: one [64][200] short buffer (x bf16, later z bf16). 25.6 KB.
//
// Fragment-permutation trick (verified r2-r9): MFMA contracts A-slot(g,s) with
// B-slot(g,s); q/k fragments carry d(g,s)=16*(s>=4)+4g+(s&3) and P/V fragments
// carry j(g,s,k2)=32k2+16*(s>=4)+4g+(s&3) -- identical bijections on both
// operands, so no cross-lane traffic anywhere.

typedef __bf16 bf16;
typedef bf16 bf16x8 __attribute__((ext_vector_type(8)));
typedef float f32x4 __attribute__((ext_vector_type(4)));

#define MFMA(a, b, c) __builtin_amdgcn_mfma_f32_16x16x32_bf16(a, b, c, 0, 0, 0)

__global__ void prep_w(const float* __restrict__ wqkv,
                       const float* __restrict__ wproj,
                       const float* __restrict__ btab,
                       bf16* __restrict__ wqkvT,
                       bf16* __restrict__ wprojT,
                       float* __restrict__ relb)
{
    const int idx = blockIdx.x * 256 + threadIdx.x;
    if (idx < 110592) {                          // wqkvT [576][192]
        const int oc = idx / 192, kk = idx - oc * 192;
        const int h = oc / 96, r = oc - h * 96;
        const int sec = r >> 5, d = r & 31;
        wqkvT[idx] = (bf16)((kk < 180 && d < 30) ? wqkv[kk * 540 + sec * 180 + h * 30 + d] : 0.f);
    } else if (idx < 147456) {                   // wprojT [192][192]
        const int r = idx - 110592;
        const int n = r / 192, k = r - n * 192;
        wprojT[r] = (bf16)((n < 180 && k < 180) ? wproj[k * 180 + n] : 0.f);
    } else if (idx < 172032) {                   // relb [6][64][64]
        const int r = idx - 147456;
        const int h = r >> 12;
        const int ij = r & 4095;
        const int i = ij >> 6, j = ij & 63;
        const int rel = ((i >> 3) - (j >> 3) + 7) * 15 + ((i & 7) - (j & 7) + 7);
        relb[r] = btab[rel * 6 + h];
    }
}

__global__ __launch_bounds__(384, 4)
void swin_mfma(const float* __restrict__ xg_all,
               const float* __restrict__ mask_all,
               const float* __restrict__ bproj,
               const bf16* __restrict__ wqkvT,
               const bf16* __restrict__ wprojT,
               const float* __restrict__ relb,
               float* __restrict__ outg)
{
    __shared__ __align__(16) short xb[64 * 200];   // x bf16, later z bf16

    const int b    = blockIdx.x;
    const int tid  = threadIdx.x;
    const int w    = tid >> 6;                     // wave = head, 0..5
    const int lane = tid & 63;
    const int l15  = lane & 15;
    const int g    = lane >> 4;                    // 0..3

    const float* xg    = xg_all + (size_t)b * 11520;
    const float* maskw = mask_all + (size_t)(b & 1023) * 4096;

    // ---- phase 1: x -> bf16 xb. Batch ALL 15 loads first, then cvt+store.
    {
        float2 xv[15];
        #pragma unroll
        for (int u = 0; u < 15; u++)
            xv[u] = *reinterpret_cast<const float2*>(xg + 2 * (tid + 384 * u));
        for (int e = tid; e < 640; e += 384) {     // zero pad cols [180..200)
            const int i = e / 10;
            ((unsigned*)(xb + i * 200 + 180))[e - i * 10] = 0u;
        }
        #pragma unroll
        for (int u = 0; u < 15; u++) {
            const int e = tid + 384 * u;
            const int i = e / 90;
            const int c = 2 * e - i * 180;
            const unsigned lo = (unsigned)__builtin_bit_cast(unsigned short, (bf16)xv[u].x);
            const unsigned hi = (unsigned)__builtin_bit_cast(unsigned short, (bf16)xv[u].y);
            *reinterpret_cast<unsigned*>(xb + i * 200 + c) = lo | (hi << 16);
        }
    }
    __syncthreads();

    const bf16* wqh = wqkvT + (size_t)(w * 96) * 192;
    const int rowoff = l15 * 192 + 8 * g;

    // ---- mask it0 prefetch: in flight across the whole qk-pass
    float4 mkc[4];
    {
        const float* mkb = maskw + l15 * 64 + 4 * g;
        #pragma unroll
        for (int jt = 0; jt < 4; jt++)
            mkc[jt] = *reinterpret_cast<const float4*>(mkb + 16 * jt);
    }

    // ---- phase 2qk: q,k for head w (swapped mfma: lane=token, regs=channels)
    bf16x8 qf[4], kf[4];                           // slot s <-> d = 16*(s>=4)+4g+(s&3)
    {
        f32x4 aqk[4][4];                           // [ct][tt] ct: q0,q1,k0,k1
        #pragma unroll
        for (int ct = 0; ct < 4; ct++)
            #pragma unroll
            for (int tt = 0; tt < 4; tt++) aqk[ct][tt] = (f32x4)0.f;
        #pragma unroll
        for (int ks = 0; ks < 6; ks++) {
            bf16x8 xf[4];
            #pragma unroll
            for (int tt = 0; tt < 4; tt++)
                xf[tt] = *reinterpret_cast<const bf16x8*>(xb + (16 * tt + l15) * 200 + 32 * ks + 8 * g);
            __builtin_amdgcn_s_setprio(1);
            #pragma unroll
            for (int ct = 0; ct < 4; ct++) {
                const bf16x8 wf = *reinterpret_cast<const bf16x8*>(wqh + ct * 3072 + rowoff + 32 * ks);
                #pragma unroll
                for (int tt = 0; tt < 4; tt++)
                    aqk[ct][tt] = MFMA(wf, xf[tt], aqk[ct][tt]);
            }
            __builtin_amdgcn_s_setprio(0);
        }
        #pragma unroll
        for (int tt = 0; tt < 4; tt++)
            #pragma unroll
            for (int s = 0; s < 8; s++) {
                qf[tt][s] = (bf16)(aqk[s >> 2][tt][s & 3] * 0.18257418583505537f);
                kf[tt][s] = (bf16)(aqk[2 + (s >> 2)][tt][s & 3]);
            }
    }
    __builtin_amdgcn_sched_barrier(0);

    // ---- phase 3: QK^T + softmax; it+1 mask/bias issued BEFORE the MFMAs
    bf16x8 pf[4][2];                               // [it][k2]
    {
        const float* relh = relb + w * 4096;
        float4 rbc[4];
        {
            const float* rbb = relh + l15 * 64 + 4 * g;
            #pragma unroll
            for (int jt = 0; jt < 4; jt++)
                rbc[jt] = *reinterpret_cast<const float4*>(rbb + 16 * jt);
        }
        #pragma unroll
        for (int it = 0; it < 4; it++) {
            float4 rbn[4], mkn[4];                 // issue next-it loads first
            if (it < 3) {
                const int i1 = 16 * (it + 1) + l15;
                const float* rbb = relh + i1 * 64 + 4 * g;
                const float* mkb = maskw + i1 * 64 + 4 * g;
                #pragma unroll
                for (int jt = 0; jt < 4; jt++) {
                    rbn[jt] = *reinterpret_cast<const float4*>(rbb + 16 * jt);
                    mkn[jt] = *reinterpret_cast<const float4*>(mkb + 16 * jt);
                }
            }

            f32x4 stj[4];                          // j = 16jt+4g+r, i = 16it+l15
            __builtin_amdgcn_s_setprio(1);
            #pragma unroll
            for (int jt = 0; jt < 4; jt++) stj[jt] = MFMA(kf[jt], qf[it], (f32x4)0.f);
            __builtin_amdgcn_s_setprio(0);

            float mx = -1e30f;
            #pragma unroll
            for (int jt = 0; jt < 4; jt++) {
                stj[jt][0] += rbc[jt].x + mkc[jt].x;
                stj[jt][1] += rbc[jt].y + mkc[jt].y;
                stj[jt][2] += rbc[jt].z + mkc[jt].z;
                stj[jt][3] += rbc[jt].w + mkc[jt].w;
                #pragma unroll
                for (int r = 0; r < 4; r++) mx = fmaxf(mx, stj[jt][r]);
            }
            mx = fmaxf(mx, __shfl_xor(mx, 16));
            mx = fmaxf(mx, __shfl_xor(mx, 32));
            float sum = 0.f;
            #pragma unroll
            for (int jt = 0; jt < 4; jt++)
                #pragma unroll
                for (int r = 0; r < 4; r++) {
                    const float e = __expf(stj[jt][r] - mx);
                    stj[jt][r] = e;
                    sum += e;
                }
            sum += __shfl_xor(sum, 16);
            sum += __shfl_xor(sum, 32);
            const float inv = 1.0f / sum;
            #pragma unroll
            for (int k2 = 0; k2 < 2; k2++)
                #pragma unroll
                for (int s = 0; s < 8; s++)
                    pf[it][k2][s] = (bf16)(stj[2 * k2 + (s >> 2)][s & 3] * inv);

            if (it < 3) {
                #pragma unroll
                for (int jt = 0; jt < 4; jt++) { rbc[jt] = rbn[jt]; mkc[jt] = mkn[jt]; }
            }
        }
    }
    // pre-issue v-pass ks0 weights (stay in flight across the fence)
    bf16x8 wv0 = *reinterpret_cast<const bf16x8*>(wqh + 4 * 3072 + rowoff);
    bf16x8 wv1 = *reinterpret_cast<const bf16x8*>(wqh + 5 * 3072 + rowoff);
    __builtin_amdgcn_sched_barrier(0);

    // ---- phase 2v (deferred): v (normal mfma: lane=channel, regs=tokens)
    bf16x8 vf[2][2];                               // [cv][k2]
    {
        f32x4 av[4][2];                            // [tt][cv]
        #pragma unroll
        for (int tt = 0; tt < 4; tt++) { av[tt][0] = (f32x4)0.f; av[tt][1] = (f32x4)0.f; }
        #pragma unroll
        for (int ks = 0; ks < 6; ks++) {
            bf16x8 xf[4];
            #pragma unroll
            for (int tt = 0; tt < 4; tt++)
                xf[tt] = *reinterpret_cast<const bf16x8*>(xb + (16 * tt + l15) * 200 + 32 * ks + 8 * g);
            __builtin_amdgcn_s_setprio(1);
            #pragma unroll
            for (int cv = 0; cv < 2; cv++) {
                const bf16x8 wf = (ks == 0)
                    ? (cv ? wv1 : wv0)
                    : *reinterpret_cast<const bf16x8*>(wqh + (4 + cv) * 3072 + rowoff + 32 * ks);
                #pragma unroll
                for (int tt = 0; tt < 4; tt++)
                    av[tt][cv] = MFMA(xf[tt], wf, av[tt][cv]);
            }
            __builtin_amdgcn_s_setprio(0);
        }
        #pragma unroll
        for (int cv = 0; cv < 2; cv++)
            #pragma unroll
            for (int k2 = 0; k2 < 2; k2++)
                #pragma unroll
                for (int s = 0; s < 8; s++)
                    vf[cv][k2][s] = (bf16)(av[2 * k2 + (s >> 2)][cv][s & 3]);
    }
    // pre-issue proj ks0 weights + bias (in flight across fence + PV + barriers)
    bf16x8 wp0 = *reinterpret_cast<const bf16x8*>(wprojT + ((2 * w + 0) * 16 + l15) * 192 + 8 * g);
    bf16x8 wp1 = *reinterpret_cast<const bf16x8*>(wprojT + ((2 * w + 1) * 16 + l15) * 192 + 8 * g);
    const int pn0 = (2 * w + 0) * 16 + l15;
    const int pn1 = (2 * w + 1) * 16 + l15;
    const float bn0 = (pn0 < 180) ? bproj[pn0] : 0.f;
    const float bn1 = (pn1 < 180) ? bproj[pn1] : 0.f;
    __builtin_amdgcn_sched_barrier(0);

    // ---- phase 4: PV, all in registers
    f32x4 zacc[4][2];                              // [it][cv]: z[16it+4g+r][16cv+l15]
    #pragma unroll
    for (int it = 0; it < 4; it++) { zacc[it][0] = (f32x4)0.f; zacc[it][1] = (f32x4)0.f; }
    __builtin_amdgcn_s_setprio(1);
    #pragma unroll
    for (int k2 = 0; k2 < 2; k2++)
        #pragma unroll
        for (int cv = 0; cv < 2; cv++)
            #pragma unroll
            for (int it = 0; it < 4; it++)
                zacc[it][cv] = MFMA(pf[it][k2], vf[cv][k2], zacc[it][cv]);
    __builtin_amdgcn_s_setprio(0);

    __syncthreads();                               // all waves done reading xb
    // z -> zb (aliases xb; pad cols [180..200) still zero from phase 1)
    #pragma unroll
    for (int cv = 0; cv < 2; cv++) {
        const int d = 16 * cv + l15;
        if (d < 30) {
            #pragma unroll
            for (int it = 0; it < 4; it++)
                #pragma unroll
                for (int r = 0; r < 4; r++)
                    xb[(16 * it + 4 * g + r) * 200 + w * 30 + d] =
                        __builtin_bit_cast(short, (bf16)zacc[it][cv][r]);
        }
    }
    __syncthreads();

    // ---- phase 5: proj GEMM + bias -> out
    f32x4 pa[4][2];
    #pragma unroll
    for (int mt = 0; mt < 4; mt++) { pa[mt][0] = (f32x4)0.f; pa[mt][1] = (f32x4)0.f; }
    #pragma unroll
    for (int ks = 0; ks < 6; ks++) {
        bf16x8 zf[4];
        #pragma unroll
        for (int mt = 0; mt < 4; mt++)
            zf[mt] = *reinterpret_cast<const bf16x8*>(xb + (16 * mt + l15) * 200 + 32 * ks + 8 * g);
        __builtin_amdgcn_s_setprio(1);
        #pragma unroll
        for (int q2 = 0; q2 < 2; q2++) {
            const bf16x8 wf = (ks == 0)
                ? (q2 ? wp1 : wp0)
                : *reinterpret_cast<const bf16x8*>(
                      wprojT + ((2 * w + q2) * 16 + l15) * 192 + 32 * ks + 8 * g);
            #pragma unroll
            for (int mt = 0; mt < 4; mt++)
                pa[mt][q2] = MFMA(zf[mt], wf, pa[mt][q2]);
        }
        __builtin_amdgcn_s_setprio(0);
    }
    #pragma unroll
    for (int q2 = 0; q2 < 2; q2++) {
        const int n = (2 * w + q2) * 16 + l15;
        if (n < 180) {
            const float bn = q2 ? bn1 : bn0;
            float* const ob = outg + (size_t)b * 11520 + n;
            #pragma unroll
            for (int mt = 0; mt < 4; mt++)
                #pragma unroll
                for (int r = 0; r < 4; r++)
                    ob[(16 * mt + 4 * g + r) * 180] = pa[mt][q2][r] + bn;
        }
    }
}

extern "C" void kernel_launch(void* const* d_in, const int* in_sizes, int n_in,
                              void* d_out, int out_size, void* d_ws, size_t ws_size,
                              hipStream_t stream) {
    const float* windows = (const float*)d_in[0];
    const float* mask    = (const float*)d_in[1];
    const float* wqkv    = (const float*)d_in[2];
    const float* btab    = (const float*)d_in[3];
    const float* wproj   = (const float*)d_in[4];
    const float* bproj   = (const float*)d_in[5];

    bf16*  wqkvT  = (bf16*)d_ws;
    bf16*  wprojT = (bf16*)((char*)d_ws + 221184);
    float* relb   = (float*)((char*)d_ws + 294912);

    hipLaunchKernelGGL(prep_w, dim3(672), dim3(256), 0, stream,
                       wqkv, wproj, btab, wqkvT, wprojT, relb);
    hipLaunchKernelGGL(swin_mfma, dim3(4096), dim3(384), 0, stream,
                       windows, mask, bproj, wqkvT, wprojT, relb, (float*)d_out);
}

// Round 11
// 285.653 us; speedup vs baseline: 1.2152x; 1.2152x over previous
//
#include <hip/hip_runtime.h>

// Swin window attention, fused register-resident MFMA pipeline. 1 block
// (6 waves) per window; wave w owns head w. B=4096, N=64, C=180, H=6, D=30.
//
// Round-11 = round-9 (290 us champion, no spill) + ZERO-REGISTER additions:
//   - s_setprio(1) around every MFMA cluster (T5; 2 blocks/CU drift out of
//     phase -> MFMA waves win issue arbitration). 0 register cost.
//   - phase-1 staging via float4 (7-8/thread) instead of float2 x15.
//   Round-10's register-holding prefetches (mask across qk, wv/wp pre-issue)
//   spilled at the 128-reg ceiling (FETCH 212MB/WRITE 352MB) -- reverted.
//
// d_ws (prep_w fills every launch):
//   [0)       wqkvT  bf16 [576][192]  oc = h*96 + sec*32 + d  (0=q,1=k,2=v)
//   [221184)  wprojT bf16 [192][192]  n-major
//   [294912)  relb   f32  [6][64][64] pre-gathered rel-pos bias
//
// LDS: one [64][200] short buffer (x bf16, later z bf16). 25.6 KB.
//
// Fragment-permutation trick (verified r2-r9): MFMA contracts A-slot(g,s) with
// B-slot(g,s); q/k fragments carry d(g,s)=16*(s>=4)+4g+(s&3) and P/V fragments
// carry j(g,s,k2)=32k2+16*(s>=4)+4g+(s&3) -- identical bijections on both
// operands, so no cross-lane traffic anywhere.

typedef __bf16 bf16;
typedef bf16 bf16x8 __attribute__((ext_vector_type(8)));
typedef float f32x4 __attribute__((ext_vector_type(4)));

#define MFMA(a, b, c) __builtin_amdgcn_mfma_f32_16x16x32_bf16(a, b, c, 0, 0, 0)

__global__ void prep_w(const float* __restrict__ wqkv,
                       const float* __restrict__ wproj,
                       const float* __restrict__ btab,
                       bf16* __restrict__ wqkvT,
                       bf16* __restrict__ wprojT,
                       float* __restrict__ relb)
{
    const int idx = blockIdx.x * 256 + threadIdx.x;
    if (idx < 110592) {                          // wqkvT [576][192]
        const int oc = idx / 192, kk = idx - oc * 192;
        const int h = oc / 96, r = oc - h * 96;
        const int sec = r >> 5, d = r & 31;
        wqkvT[idx] = (bf16)((kk < 180 && d < 30) ? wqkv[kk * 540 + sec * 180 + h * 30 + d] : 0.f);
    } else if (idx < 147456) {                   // wprojT [192][192]
        const int r = idx - 110592;
        const int n = r / 192, k = r - n * 192;
        wprojT[r] = (bf16)((n < 180 && k < 180) ? wproj[k * 180 + n] : 0.f);
    } else if (idx < 172032) {                   // relb [6][64][64]
        const int r = idx - 147456;
        const int h = r >> 12;
        const int ij = r & 4095;
        const int i = ij >> 6, j = ij & 63;
        const int rel = ((i >> 3) - (j >> 3) + 7) * 15 + ((i & 7) - (j & 7) + 7);
        relb[r] = btab[rel * 6 + h];
    }
}

__global__ __launch_bounds__(384, 4)
void swin_mfma(const float* __restrict__ xg_all,
               const float* __restrict__ mask_all,
               const float* __restrict__ bproj,
               const bf16* __restrict__ wqkvT,
               const bf16* __restrict__ wprojT,
               const float* __restrict__ relb,
               float* __restrict__ outg)
{
    __shared__ __align__(16) short xb[64 * 200];   // x bf16, later z bf16

    const int b    = blockIdx.x;
    const int tid  = threadIdx.x;
    const int w    = tid >> 6;                     // wave = head, 0..5
    const int lane = tid & 63;
    const int l15  = lane & 15;
    const int g    = lane >> 4;                    // 0..3

    const float* xg    = xg_all + (size_t)b * 11520;
    const float* maskw = mask_all + (size_t)(b & 1023) * 4096;

    // ---- phase 1: x -> bf16 xb. Batch loads (7-8 float4/thread), then cvt.
    // 11520 f32 = 2880 float4; rows are 45 float4 each (no row-crossing).
    {
        float4 xv[7];
        #pragma unroll
        for (int u = 0; u < 7; u++)
            xv[u] = *reinterpret_cast<const float4*>(xg + 4 * (tid + 384 * u));
        float4 xt;
        if (tid < 192) xt = *reinterpret_cast<const float4*>(xg + 4 * (2688 + tid));
        for (int e = tid; e < 640; e += 384) {     // zero pad cols [180..200)
            const int i = e / 10;
            ((unsigned*)(xb + i * 200 + 180))[e - i * 10] = 0u;
        }
        #pragma unroll
        for (int u = 0; u < 7; u++) {
            const int e = tid + 384 * u;           // float4 index
            const int i = e / 45;
            const int c = 4 * e - i * 180;
            const unsigned p0 = (unsigned)__builtin_bit_cast(unsigned short, (bf16)xv[u].x)
                              | ((unsigned)__builtin_bit_cast(unsigned short, (bf16)xv[u].y) << 16);
            const unsigned p1 = (unsigned)__builtin_bit_cast(unsigned short, (bf16)xv[u].z)
                              | ((unsigned)__builtin_bit_cast(unsigned short, (bf16)xv[u].w) << 16);
            *reinterpret_cast<unsigned*>(xb + i * 200 + c)     = p0;
            *reinterpret_cast<unsigned*>(xb + i * 200 + c + 2) = p1;
        }
        if (tid < 192) {
            const int e = 2688 + tid;
            const int i = e / 45;
            const int c = 4 * e - i * 180;
            const unsigned p0 = (unsigned)__builtin_bit_cast(unsigned short, (bf16)xt.x)
                              | ((unsigned)__builtin_bit_cast(unsigned short, (bf16)xt.y) << 16);
            const unsigned p1 = (unsigned)__builtin_bit_cast(unsigned short, (bf16)xt.z)
                              | ((unsigned)__builtin_bit_cast(unsigned short, (bf16)xt.w) << 16);
            *reinterpret_cast<unsigned*>(xb + i * 200 + c)     = p0;
            *reinterpret_cast<unsigned*>(xb + i * 200 + c + 2) = p1;
        }
    }
    __syncthreads();

    const bf16* wqh = wqkvT + (size_t)(w * 96) * 192;
    const int rowoff = l15 * 192 + 8 * g;

    // ---- phase 2qk: q,k for head w (swapped mfma: lane=token, regs=channels)
    bf16x8 qf[4], kf[4];                           // slot s <-> d = 16*(s>=4)+4g+(s&3)
    {
        f32x4 aqk[4][4];                           // [ct][tt] ct: q0,q1,k0,k1
        #pragma unroll
        for (int ct = 0; ct < 4; ct++)
            #pragma unroll
            for (int tt = 0; tt < 4; tt++) aqk[ct][tt] = (f32x4)0.f;
        #pragma unroll
        for (int ks = 0; ks < 6; ks++) {
            bf16x8 xf[4];
            #pragma unroll
            for (int tt = 0; tt < 4; tt++)
                xf[tt] = *reinterpret_cast<const bf16x8*>(xb + (16 * tt + l15) * 200 + 32 * ks + 8 * g);
            __builtin_amdgcn_s_setprio(1);
            #pragma unroll
            for (int ct = 0; ct < 4; ct++) {
                const bf16x8 wf = *reinterpret_cast<const bf16x8*>(wqh + ct * 3072 + rowoff + 32 * ks);
                #pragma unroll
                for (int tt = 0; tt < 4; tt++)
                    aqk[ct][tt] = MFMA(wf, xf[tt], aqk[ct][tt]);
            }
            __builtin_amdgcn_s_setprio(0);
        }
        #pragma unroll
        for (int tt = 0; tt < 4; tt++)
            #pragma unroll
            for (int s = 0; s < 8; s++) {
                qf[tt][s] = (bf16)(aqk[s >> 2][tt][s & 3] * 0.18257418583505537f);
                kf[tt][s] = (bf16)(aqk[2 + (s >> 2)][tt][s & 3]);
            }
    }
    __builtin_amdgcn_sched_barrier(0);

    // ---- phase 3: QK^T + softmax, it-sequential, bias prefetched 1 it ahead
    bf16x8 pf[4][2];                               // [it][k2]
    {
        const float* relh = relb + w * 4096;
        float4 rbc[4], mkc[4];                     // current-it bias (prefetched)
        {
            const float* rbb = relh + l15 * 64 + 4 * g;
            const float* mkb = maskw + l15 * 64 + 4 * g;
            #pragma unroll
            for (int jt = 0; jt < 4; jt++) {
                rbc[jt] = *reinterpret_cast<const float4*>(rbb + 16 * jt);
                mkc[jt] = *reinterpret_cast<const float4*>(mkb + 16 * jt);
            }
        }
        #pragma unroll
        for (int it = 0; it < 4; it++) {
            f32x4 stj[4];                          // j = 16jt+4g+r, i = 16it+l15
            __builtin_amdgcn_s_setprio(1);
            #pragma unroll
            for (int jt = 0; jt < 4; jt++) stj[jt] = MFMA(kf[jt], qf[it], (f32x4)0.f);
            __builtin_amdgcn_s_setprio(0);

            float4 rbn[4], mkn[4];                 // prefetch next it's bias
            if (it < 3) {
                const int i1 = 16 * (it + 1) + l15;
                const float* rbb = relh + i1 * 64 + 4 * g;
                const float* mkb = maskw + i1 * 64 + 4 * g;
                #pragma unroll
                for (int jt = 0; jt < 4; jt++) {
                    rbn[jt] = *reinterpret_cast<const float4*>(rbb + 16 * jt);
                    mkn[jt] = *reinterpret_cast<const float4*>(mkb + 16 * jt);
                }
            }

            float mx = -1e30f;
            #pragma unroll
            for (int jt = 0; jt < 4; jt++) {
                stj[jt][0] += rbc[jt].x + mkc[jt].x;
                stj[jt][1] += rbc[jt].y + mkc[jt].y;
                stj[jt][2] += rbc[jt].z + mkc[jt].z;
                stj[jt][3] += rbc[jt].w + mkc[jt].w;
                #pragma unroll
                for (int r = 0; r < 4; r++) mx = fmaxf(mx, stj[jt][r]);
            }
            mx = fmaxf(mx, __shfl_xor(mx, 16));
            mx = fmaxf(mx, __shfl_xor(mx, 32));
            float sum = 0.f;
            #pragma unroll
            for (int jt = 0; jt < 4; jt++)
                #pragma unroll
                for (int r = 0; r < 4; r++) {
                    const float e = __expf(stj[jt][r] - mx);
                    stj[jt][r] = e;
                    sum += e;
                }
            sum += __shfl_xor(sum, 16);
            sum += __shfl_xor(sum, 32);
            const float inv = 1.0f / sum;
            #pragma unroll
            for (int k2 = 0; k2 < 2; k2++)
                #pragma unroll
                for (int s = 0; s < 8; s++)
                    pf[it][k2][s] = (bf16)(stj[2 * k2 + (s >> 2)][s & 3] * inv);

            if (it < 3) {
                #pragma unroll
                for (int jt = 0; jt < 4; jt++) { rbc[jt] = rbn[jt]; mkc[jt] = mkn[jt]; }
            }
        }
    }
    __builtin_amdgcn_sched_barrier(0);

    // ---- phase 2v (deferred): v (normal mfma: lane=channel, regs=tokens)
    bf16x8 vf[2][2];                               // [cv][k2]
    {
        f32x4 av[4][2];                            // [tt][cv]
        #pragma unroll
        for (int tt = 0; tt < 4; tt++) { av[tt][0] = (f32x4)0.f; av[tt][1] = (f32x4)0.f; }
        #pragma unroll
        for (int ks = 0; ks < 6; ks++) {
            bf16x8 xf[4];
            #pragma unroll
            for (int tt = 0; tt < 4; tt++)
                xf[tt] = *reinterpret_cast<const bf16x8*>(xb + (16 * tt + l15) * 200 + 32 * ks + 8 * g);
            __builtin_amdgcn_s_setprio(1);
            #pragma unroll
            for (int cv = 0; cv < 2; cv++) {
                const bf16x8 wf = *reinterpret_cast<const bf16x8*>(wqh + (4 + cv) * 3072 + rowoff + 32 * ks);
                #pragma unroll
                for (int tt = 0; tt < 4; tt++)
                    av[tt][cv] = MFMA(xf[tt], wf, av[tt][cv]);
            }
            __builtin_amdgcn_s_setprio(0);
        }
        #pragma unroll
        for (int cv = 0; cv < 2; cv++)
            #pragma unroll
            for (int k2 = 0; k2 < 2; k2++)
                #pragma unroll
                for (int s = 0; s < 8; s++)
                    vf[cv][k2][s] = (bf16)(av[2 * k2 + (s >> 2)][cv][s & 3]);
    }
    __builtin_amdgcn_sched_barrier(0);

    // ---- phase 4: PV, all in registers
    f32x4 zacc[4][2];                              // [it][cv]: z[16it+4g+r][16cv+l15]
    #pragma unroll
    for (int it = 0; it < 4; it++) { zacc[it][0] = (f32x4)0.f; zacc[it][1] = (f32x4)0.f; }
    __builtin_amdgcn_s_setprio(1);
    #pragma unroll
    for (int k2 = 0; k2 < 2; k2++)
        #pragma unroll
        for (int cv = 0; cv < 2; cv++)
            #pragma unroll
            for (int it = 0; it < 4; it++)
                zacc[it][cv] = MFMA(pf[it][k2], vf[cv][k2], zacc[it][cv]);
    __builtin_amdgcn_s_setprio(0);

    __syncthreads();                               // all waves done reading xb
    // z -> zb (aliases xb; pad cols [180..200) still zero from phase 1)
    #pragma unroll
    for (int cv = 0; cv < 2; cv++) {
        const int d = 16 * cv + l15;
        if (d < 30) {
            #pragma unroll
            for (int it = 0; it < 4; it++)
                #pragma unroll
                for (int r = 0; r < 4; r++)
                    xb[(16 * it + 4 * g + r) * 200 + w * 30 + d] =
                        __builtin_bit_cast(short, (bf16)zacc[it][cv][r]);
        }
    }
    __syncthreads();

    // ---- phase 5: proj GEMM + bias -> out
    f32x4 pa[4][2];
    #pragma unroll
    for (int mt = 0; mt < 4; mt++) { pa[mt][0] = (f32x4)0.f; pa[mt][1] = (f32x4)0.f; }
    #pragma unroll
    for (int ks = 0; ks < 6; ks++) {
        bf16x8 zf[4];
        #pragma unroll
        for (int mt = 0; mt < 4; mt++)
            zf[mt] = *reinterpret_cast<const bf16x8*>(xb + (16 * mt + l15) * 200 + 32 * ks + 8 * g);
        __builtin_amdgcn_s_setprio(1);
        #pragma unroll
        for (int q2 = 0; q2 < 2; q2++) {
            const bf16x8 wf = *reinterpret_cast<const bf16x8*>(
                wprojT + ((2 * w + q2) * 16 + l15) * 192 + 32 * ks + 8 * g);
            #pragma unroll
            for (int mt = 0; mt < 4; mt++)
                pa[mt][q2] = MFMA(zf[mt], wf, pa[mt][q2]);
        }
        __builtin_amdgcn_s_setprio(0);
    }
    #pragma unroll
    for (int q2 = 0; q2 < 2; q2++) {
        const int n = (2 * w + q2) * 16 + l15;
        if (n < 180) {
            const float bn = bproj[n];
            float* const ob = outg + (size_t)b * 11520 + n;
            #pragma unroll
            for (int mt = 0; mt < 4; mt++)
                #pragma unroll
                for (int r = 0; r < 4; r++)
                    ob[(16 * mt + 4 * g + r) * 180] = pa[mt][q2][r] + bn;
        }
    }
}

extern "C" void kernel_launch(void* const* d_in, const int* in_sizes, int n_in,
                              void* d_out, int out_size, void* d_ws, size_t ws_size,
                              hipStream_t stream) {
    const float* windows = (const float*)d_in[0];
    const float* mask    = (const float*)d_in[1];
    const float* wqkv    = (const float*)d_in[2];
    const float* btab    = (const float*)d_in[3];
    const float* wproj   = (const float*)d_in[4];
    const float* bproj   = (const float*)d_in[5];

    bf16*  wqkvT  = (bf16*)d_ws;
    bf16*  wprojT = (bf16*)((char*)d_ws + 221184);
    float* relb   = (float*)((char*)d_ws + 294912);

    hipLaunchKernelGGL(prep_w, dim3(672), dim3(256), 0, stream,
                       wqkv, wproj, btab, wqkvT, wprojT, relb);
    hipLaunchKernelGGL(swin_mfma, dim3(4096), dim3(384), 0, stream,
                       windows, mask, bproj, wqkvT, wprojT, relb, (float*)d_out);
}